// Round 8
// baseline (1503.693 us; speedup 1.0000x reference)
//
#include <hip/hip_runtime.h>

#define IMG   512
#define RTILE 112         // output tile per block
#define RHALO 8           // halo = steps per round (8 then 7)
#define RBUF  128         // logical buffer rows/cols = RTILE + 2*RHALO
#define RLW   132         // physical row stride in words (mult of 4)
#define PHYSR 131         // physical rows: logical -1..129
#define LDSW  (4 + PHYSR * RLW)   // +4 front pad for col -1 of phys row 0

__device__ __forceinline__ float mapf(float g) {
    float t = 3.9f * g;
    return t - t * g;          // R*g*(1-g)
}

// 6-word stencil window (cols xc-1 .. xc+4) at physical row pointer p:
// one aligned b128 + two scalars (merge to ds_read2_b32).
__device__ __forceinline__ void rrow6(const float* __restrict__ p, float* m) {
    const float4 mid = *(const float4*)p;
    m[0] = p[-1];
    m[1] = mid.x; m[2] = mid.y; m[3] = mid.z; m[4] = mid.w;
    m[5] = p[4];
}

// One temporal round: init M=map(src), run `steps` CML steps, store grid to dst
// (clipped if do_clip). Valid output region = tile interior [8,120)^2.
// 512 threads; each owns a 4-wide x 8-tall patch.
// LDS (69.6 KB) caps occupancy at 2 blocks/CU = 4 waves/EU, which permits
// 128 VGPRs/thread. The backend's occupancy heuristic ignores this and
// allocates 64 (R6/R7: ~500 MB spill traffic). amdgpu_num_vgpr(128) is the
// HARD budget override (waves_per_eu(4,4) was ignored in R7).
__global__ __launch_bounds__(512, 2) __attribute__((amdgpu_num_vgpr(128)))
void cml_round(
    const float* __restrict__ src,     // g_t  (round 1: drive, since g0 = drive)
    const float* __restrict__ drv,
    const float* __restrict__ Kw,
    float* __restrict__ dst,
    int steps, int do_clip)
{
    __shared__ float lds_raw[LDSW];    // 69.2 KiB -> 2 blocks/CU
    float* __restrict__ B = lds_raw + 4;   // phys row r, col c: B[r*RLW + c]

    const int tid = threadIdx.x;
    const int bid = blockIdx.x;
    const int bc  = bid / 25;               // image*channel index
    const int tl  = bid % 25;               // 5x5 tiles of 112
    const int gy0 = (tl / 5) * RTILE - RHALO;   // logical buffer row 0 -> gy0
    const int gx0 = (tl % 5) * RTILE - RHALO;   // multiple of 4
    const float* __restrict__ simg = src + (size_t)bc * (IMG*IMG);
    const float* __restrict__ dimg = drv + (size_t)bc * (IMG*IMG);
    float*       __restrict__ oimg = dst + (size_t)bc * (IMG*IMG);

    // Folded 3x3 kernel: K' = (0.85*0.3)*K + (0.85*0.7)*delta_center
    float kk[9];
    {
        const float c2 = 0.85f * 0.3f;
        const float* kp = Kw + (bc & 3) * 9;
#pragma unroll
        for (int q = 0; q < 9; q++) kk[q] = c2 * kp[q];
        kk[4] += 0.85f * 0.7f;
    }

    const int pj = tid & 31;                // col patch: owned cols 4pj..4pj+3
    const int pi = tid >> 5;                // row band:  owned rows 8pi..8pi+7
    const int y0 = pi * 8;
    const int xc = pj * 4;

    // Boundary flags + beta*drive for owned cells (registers)
    float fx[4], fy[8], dvs[32];
#pragma unroll
    for (int k = 0; k < 4; k++)
        fx[k] = ((unsigned)(gx0 + xc + k) < IMG) ? 1.0f : 0.0f;
#pragma unroll
    for (int rr = 0; rr < 8; rr++) {
        const int gy = gy0 + y0 + rr;
        fy[rr] = ((unsigned)gy < IMG) ? 1.0f : 0.0f;
#pragma unroll
        for (int k = 0; k < 4; k++) {
            const int gx = gx0 + xc + k;
            dvs[rr*4+k] = (((unsigned)gy < IMG) && ((unsigned)gx < IMG))
                        ? 0.15f * dimg[gy*IMG + gx] : 0.0f;
        }
    }

    if (tid < 4) lds_raw[tid] = 0.0f;       // front pad (col -1 of phys row 0)
    // Init: B = map(src) over phys rows 0..130 (logical -1..129); pad cols -> 0.
    for (int u = tid; u < PHYSR * (RLW/4); u += 512) {
        const int r  = u / (RLW/4);
        const int xq = (u - r * (RLW/4)) * 4;
        const int gy  = gy0 + r - 1;
        const int gxb = gx0 + xq;               // mult of 4 -> aligned float4
        float4 v = make_float4(0.f, 0.f, 0.f, 0.f);
        if (xq < RBUF && (unsigned)gy < IMG && (unsigned)gxb < IMG)
            v = *(const float4*)(simg + gy*IMG + gxb);   // gxb<=508: no row cross
        v.x = mapf(v.x); v.y = mapf(v.y); v.z = mapf(v.z); v.w = mapf(v.w);
        *(float4*)(B + r*RLW + xq) = v;
    }
    __syncthreads();

    float st[32];
#pragma unroll 1
    for (int step = 0; step < steps - 1; step++) {
        {
            float a[6], b[6], c[6];
            const float* p = B + y0 * RLW + xc;     // phys y0 = logical y0-1
            rrow6(p, a);  p += RLW;
            rrow6(p, b);
#pragma unroll
            for (int rr = 0; rr < 8; rr++) {
                p += RLW;
                rrow6(p, c);
                const float fyr = fy[rr];
#pragma unroll
                for (int k = 0; k < 4; k++) {
                    float s = dvs[rr*4+k];
                    s += kk[0]*a[k] + kk[1]*a[k+1] + kk[2]*a[k+2];
                    s += kk[3]*b[k] + kk[4]*b[k+1] + kk[5]*b[k+2];
                    s += kk[6]*c[k] + kk[7]*c[k+1] + kk[8]*c[k+2];
                    const float t = 3.9f * s;
                    st[rr*4+k] = (t - t*s) * fyr * fx[k];
                }
#pragma unroll
                for (int q = 0; q < 6; q++) { a[q] = b[q]; b[q] = c[q]; }
            }
        }
        __syncthreads();   // all reads done before any write (WAR)
        {
            float* w = B + (y0 + 1) * RLW + xc;     // phys y0+1 = logical y0
#pragma unroll
            for (int rr = 0; rr < 8; rr++) {
                *(float4*)w = make_float4(st[rr*4+0], st[rr*4+1],
                                          st[rr*4+2], st[rr*4+3]);
                w += RLW;
            }
        }
        __syncthreads();   // writes done before next step's reads (RAW)
    }

    // Final step of the round: compute grid (no map), store valid interior.
    {
        float a[6], b[6], c[6];
        const float* p = B + y0 * RLW + xc;
        rrow6(p, a);  p += RLW;
        rrow6(p, b);
#pragma unroll
        for (int rr = 0; rr < 8; rr++) {
            p += RLW;
            rrow6(p, c);
#pragma unroll
            for (int k = 0; k < 4; k++) {
                float s = dvs[rr*4+k];
                s += kk[0]*a[k] + kk[1]*a[k+1] + kk[2]*a[k+2];
                s += kk[3]*b[k] + kk[4]*b[k+1] + kk[5]*b[k+2];
                s += kk[6]*c[k] + kk[7]*c[k+1] + kk[8]*c[k+2];
                st[rr*4+k] = s;
            }
#pragma unroll
            for (int q = 0; q < 6; q++) { a[q] = b[q]; b[q] = c[q]; }
        }
    }
    // Valid region: buffer [8,120)^2 -> pj in [2,29], pi in [1,14].
    if (pi >= 1 && pi <= 14 && pj >= 2 && pj <= 29) {
        const int gxb = gx0 + xc;               // mult of 4; >= 0 since pj>=2
        if (gxb + 3 < IMG) {                    // skip phantom cols of edge tiles
#pragma unroll
            for (int rr = 0; rr < 8; rr++) {
                const int gy = gy0 + y0 + rr;   // >= 0 always (pi>=1)
                if (gy < IMG) {
                    float4 v = make_float4(st[rr*4+0], st[rr*4+1],
                                           st[rr*4+2], st[rr*4+3]);
                    if (do_clip) {
                        v.x = fminf(fmaxf(v.x, 1e-4f), 1.0f - 1e-4f);
                        v.y = fminf(fmaxf(v.y, 1e-4f), 1.0f - 1e-4f);
                        v.z = fminf(fmaxf(v.z, 1e-4f), 1.0f - 1e-4f);
                        v.w = fminf(fmaxf(v.w, 1e-4f), 1.0f - 1e-4f);
                    }
                    *(float4*)(oimg + gy*IMG + gxb) = v;
                }
            }
        }
    }
}

// ---------------- Fallback: single-kernel 15-step version (Round-4) ----------
#define TILE  128
#define OFF_Y 16
#define OFF_X 18
#define BUFY  160
#define BUFX  164
#define LW    172
#define NP    1014

__device__ __forceinline__ void read_row6(const float* __restrict__ p, int xw,
                                          float* m) {
    const float4 mid = *(const float4*)(p + xw + 4);
    m[0] = p[xw + 3];
    m[1] = mid.x; m[2] = mid.y; m[3] = mid.z; m[4] = mid.w;
    m[5] = p[xw + 8];
}

__global__ __launch_bounds__(1024, 4) void cml_fused(
    const float* __restrict__ drive,
    const float* __restrict__ Kw,
    float* __restrict__ out)
{
    __shared__ float lds[BUFY * LW];
    const int tid = threadIdx.x;
    const int bid = blockIdx.x;
    const int bc  = bid >> 4;
    const int tl  = bid & 15;
    const int gy0 = (tl >> 2) * TILE - OFF_Y;
    const int gx0 = (tl & 3)  * TILE - OFF_X;
    const float* __restrict__ img  = drive + (size_t)bc * (IMG*IMG);
    float*       __restrict__ oimg = out   + (size_t)bc * (IMG*IMG);
    float kk[9];
    {
        const float c2 = 0.85f * 0.3f;
        const float* kp = Kw + (bc & 3) * 9;
#pragma unroll
        for (int q = 0; q < 9; q++) kk[q] = c2 * kp[q];
        kk[4] += 0.85f * 0.7f;
    }
    const int t2 = tid < NP ? tid : NP - 1;
    const int pi = t2 / 39;
    const int pj = t2 - pi * 39;
    const int y0 = 2 + 6 * pi;
    const int xw = 4 * pj;
    float dvs[24], fx[4], fy[6];
#pragma unroll
    for (int k = 0; k < 4; k++)
        fx[k] = ((unsigned)(gx0 + xw + 4 + k) < IMG) ? 1.0f : 0.0f;
#pragma unroll
    for (int rr = 0; rr < 6; rr++) {
        const int gy = gy0 + y0 + rr;
        fy[rr] = ((unsigned)gy < IMG) ? 1.0f : 0.0f;
#pragma unroll
        for (int k = 0; k < 4; k++) {
            const int gx = gx0 + xw + 4 + k;
            dvs[rr*4+k] = (((unsigned)gy < IMG) && ((unsigned)gx < IMG))
                        ? 0.15f * img[gy*IMG + gx] : 0.0f;
        }
    }
    for (int u = tid; u < BUFY * (LW/2); u += 1024) {
        const int yy = u / (LW/2);
        const int xx = (u - yy * (LW/2)) * 2;
        const int gy = gy0 + yy;
        const int gxb = gx0 + xx;
        float2 v = make_float2(0.f, 0.f);
        if (xx < BUFX && (unsigned)gy < IMG && (unsigned)gxb < IMG)
            v = *(const float2*)(img + gy*IMG + gxb);
        v.x = mapf(v.x); v.y = mapf(v.y);
        *(float2*)(lds + yy*LW + xx) = v;
    }
    __syncthreads();
    float st[24];
#pragma unroll 1
    for (int step = 0; step < 14; step++) {
        {
            float a[6], b[6], c[6];
            const float* p = lds + (y0 - 1) * LW;
            read_row6(p, xw, a);  p += LW;
            read_row6(p, xw, b);
#pragma unroll
            for (int rr = 0; rr < 6; rr++) {
                p += LW;
                read_row6(p, xw, c);
                const float fyr = fy[rr];
#pragma unroll
                for (int k = 0; k < 4; k++) {
                    float s = dvs[rr*4+k];
                    s += kk[0]*a[k] + kk[1]*a[k+1] + kk[2]*a[k+2];
                    s += kk[3]*b[k] + kk[4]*b[k+1] + kk[5]*b[k+2];
                    s += kk[6]*c[k] + kk[7]*c[k+1] + kk[8]*c[k+2];
                    const float t = 3.9f * s;
                    st[rr*4+k] = (t - t*s) * fyr * fx[k];
                }
#pragma unroll
                for (int q = 0; q < 6; q++) { a[q] = b[q]; b[q] = c[q]; }
            }
        }
        __syncthreads();
        {
            float* w = lds + y0 * LW + xw + 4;
#pragma unroll
            for (int rr = 0; rr < 6; rr++) {
                *(float4*)w = make_float4(st[rr*4+0], st[rr*4+1],
                                          st[rr*4+2], st[rr*4+3]);
                w += LW;
            }
        }
        __syncthreads();
    }
    {
        float a[6], b[6], c[6];
        const float* p = lds + (y0 - 1) * LW;
        read_row6(p, xw, a);  p += LW;
        read_row6(p, xw, b);
#pragma unroll
        for (int rr = 0; rr < 6; rr++) {
            p += LW;
            read_row6(p, xw, c);
#pragma unroll
            for (int k = 0; k < 4; k++) {
                float s = dvs[rr*4+k];
                s += kk[0]*a[k] + kk[1]*a[k+1] + kk[2]*a[k+2];
                s += kk[3]*b[k] + kk[4]*b[k+1] + kk[5]*b[k+2];
                s += kk[6]*c[k] + kk[7]*c[k+1] + kk[8]*c[k+2];
                st[rr*4+k] = fminf(fmaxf(s, 1e-4f), 1.0f - 1e-4f);
            }
#pragma unroll
            for (int q = 0; q < 6; q++) { a[q] = b[q]; b[q] = c[q]; }
        }
    }
#pragma unroll
    for (int rr = 0; rr < 6; rr++) {
        const int r = y0 + rr;
        if (r >= OFF_Y && r < OFF_Y + TILE) {
#pragma unroll
            for (int h = 0; h < 2; h++) {
                const int col = xw + 4 + 2*h;
                if (col >= OFF_X && col + 1 < OFF_X + TILE) {
                    *(float2*)(oimg + (size_t)(gy0 + r) * IMG + (gx0 + col)) =
                        make_float2(st[rr*4 + 2*h], st[rr*4 + 2*h + 1]);
                }
            }
        }
    }
}

extern "C" void kernel_launch(void* const* d_in, const int* in_sizes, int n_in,
                              void* d_out, int out_size, void* d_ws, size_t ws_size,
                              hipStream_t stream)
{
    const float* drive = (const float*)d_in[0];
    const float* Kw    = (const float*)d_in[1];
    float* out         = (float*)d_out;
    const size_t need  = (size_t)256 * IMG * IMG * sizeof(float);  // 256 MiB

    if (ws_size >= need) {
        float* g8 = (float*)d_ws;
        // Round 1: g0=drive, 8 steps -> g8 (unclipped) in ws
        cml_round<<<dim3(6400), dim3(512), 0, stream>>>(drive, drive, Kw, g8, 8, 0);
        // Round 2: g8, 7 steps -> clipped g15 in out
        cml_round<<<dim3(6400), dim3(512), 0, stream>>>(g8, drive, Kw, out, 7, 1);
    } else {
        cml_fused<<<dim3(4096), dim3(1024), 0, stream>>>(drive, Kw, out);
    }
}

// Round 9
// 1196.912 us; speedup vs baseline: 1.2563x; 1.2563x over previous
//
#include <hip/hip_runtime.h>

#define IMG  512
#define RT   112          // output tile per block
#define RH   8            // halo = max steps per round
#define RLW  132          // row stride dwords: [L][4 slots x 32][R][pad 2]
#define PR   130          // phys rows: logical -1..128

__device__ __forceinline__ float mapf(float g) {
    float t = 3.9f * g;
    return t - t * g;     // R*g*(1-g)
}

// SoA address of logical col c (c in [0,128)): 1 + (c&3)*32 + (c>>2).
// Col -1 -> 0, col 128 -> 129. Stencil window cols 4pj-1..4pj+4:
#define LOADROW(P, M) do {                                   \
    const float* _p = (P);                                   \
    (M)[0] = (pj == 0)  ? _p[0]   : _p[96 + pj];             \
    (M)[1] = _p[1 + pj];                                     \
    (M)[2] = _p[33 + pj];                                    \
    (M)[3] = _p[65 + pj];                                    \
    (M)[4] = _p[97 + pj];                                    \
    (M)[5] = (pj == 31) ? _p[129] : _p[2 + pj];              \
} while (0)

// One temporal round: init M=map(src), run `steps` CML steps, store grid to
// dst (clipped if do_clip). Valid output region = tile interior [8,120)^2.
// 1024 threads, each owns a 4-wide x 4-tall patch. SoA LDS layout makes all
// steady-state LDS traffic stride-1 (conflict-free). 68.6 KB LDS -> 2
// blocks/CU = 100% wave occupancy; per-thread state ~60 regs fits the
// default 64-VGPR budget (no spills, no allocator attributes).
__global__ __launch_bounds__(1024) void cml_round(
    const float* __restrict__ src,
    const float* __restrict__ drv,
    const float* __restrict__ Kw,
    float* __restrict__ dst,
    int steps, int do_clip)
{
    __shared__ float B[PR * RLW];      // 68.6 KiB

    const int tid = threadIdx.x;
    const int bid = blockIdx.x;
    const int bc  = bid / 25;               // image*channel index
    const int tl  = bid % 25;               // 5x5 tiles of 112
    const int gy0 = (tl / 5) * RT - RH;     // logical buffer row 0 -> gy0
    const int gx0 = (tl % 5) * RT - RH;     // multiple of 4
    const float* __restrict__ simg = src + (size_t)bc * (IMG*IMG);
    const float* __restrict__ dimg = drv + (size_t)bc * (IMG*IMG);
    float*       __restrict__ oimg = dst + (size_t)bc * (IMG*IMG);

    // Folded 3x3 kernel: K' = (0.85*0.3)*K + (0.85*0.7)*delta_center.
    // bc is block-uniform -> these should be s_loads into SGPRs.
    float kk[9];
    {
        const float c2 = 0.85f * 0.3f;
        const float* kp = Kw + (bc & 3) * 9;
#pragma unroll
        for (int q = 0; q < 9; q++) kk[q] = c2 * kp[q];
        kk[4] += 0.85f * 0.7f;
    }

    const int pj  = tid & 31;               // col patch: owned cols 4pj..4pj+3
    const int pi  = tid >> 5;               // row band:  owned rows 4pi..4pi+3
    const int y0  = pi * 4;
    const int gxb = gx0 + pj * 4;           // global col of owned float4

    // Init: B = map(src) over phys rows 0..129 (logical -1..128), SoA layout.
    for (int u = tid; u < PR * 32; u += 1024) {
        const int r = u >> 5;
        const int p = u & 31;
        const int gy  = gy0 + r - 1;
        const int gxq = gx0 + p * 4;        // mult of 4 -> aligned float4
        const bool rowok = (unsigned)gy < IMG;
        float4 v = make_float4(0.f, 0.f, 0.f, 0.f);
        if (rowok && (unsigned)gxq < IMG)
            v = *(const float4*)(simg + gy*IMG + gxq);   // gxq<=508: no row cross
        float* row = B + r * RLW;
        row[1 +  0 + p] = mapf(v.x);        // stride-1 across lanes
        row[1 + 32 + p] = mapf(v.y);
        row[1 + 64 + p] = mapf(v.z);
        row[1 + 96 + p] = mapf(v.w);
        if (p == 0) {                       // left ext col (-1)
            float e = (rowok && (unsigned)(gx0 - 1) < IMG)
                    ? simg[gy*IMG + gx0 - 1] : 0.f;
            row[0] = mapf(e);
        }
        if (p == 31) {                      // right ext col (128)
            float e = (rowok && (unsigned)(gx0 + 128) < IMG)
                    ? simg[gy*IMG + gx0 + 128] : 0.f;
            row[129] = mapf(e);
        }
    }
    __syncthreads();

    float st[16];
#pragma unroll 1
    for (int step = 0; step < steps - 1; step++) {
        {
            // boundary col flags, recomputed (saves registers)
            float fx[4];
#pragma unroll
            for (int k = 0; k < 4; k++)
                fx[k] = ((unsigned)(gxb + k) < IMG) ? 1.0f : 0.0f;

            float a[6], b6[6], c6[6];
            const float* p = B + y0 * RLW;      // phys y0 = logical y0-1
            LOADROW(p, a);  p += RLW;
            LOADROW(p, b6);
#pragma unroll
            for (int rr = 0; rr < 4; rr++) {
                p += RLW;
                LOADROW(p, c6);
                const int gy = gy0 + y0 + rr;
                const bool rowok = (unsigned)gy < IMG;
                float4 dv = make_float4(0.f, 0.f, 0.f, 0.f);
                if (rowok && (unsigned)gxb < IMG)
                    dv = *(const float4*)(dimg + gy*IMG + gxb);
                const float fyr = rowok ? 1.0f : 0.0f;
                const float dva[4] = {dv.x, dv.y, dv.z, dv.w};
#pragma unroll
                for (int k = 0; k < 4; k++) {
                    float s = 0.15f * dva[k];
                    s += kk[0]*a[k]  + kk[1]*a[k+1]  + kk[2]*a[k+2];
                    s += kk[3]*b6[k] + kk[4]*b6[k+1] + kk[5]*b6[k+2];
                    s += kk[6]*c6[k] + kk[7]*c6[k+1] + kk[8]*c6[k+2];
                    const float t = 3.9f * s;
                    st[rr*4+k] = (t - t*s) * (fyr * fx[k]);
                }
#pragma unroll
                for (int q = 0; q < 6; q++) { a[q] = b6[q]; b6[q] = c6[q]; }
            }
        }
        __syncthreads();   // all reads done before any write (WAR)
#pragma unroll
        for (int rr = 0; rr < 4; rr++) {
            float* w = B + (y0 + 1 + rr) * RLW + 1 + pj;   // stride-1 lanes
            w[0]  = st[rr*4+0];
            w[32] = st[rr*4+1];
            w[64] = st[rr*4+2];
            w[96] = st[rr*4+3];
        }
        __syncthreads();   // writes done before next step's reads (RAW)
    }

    // Final step of the round: compute grid (no map), store valid interior.
    {
        float a[6], b6[6], c6[6];
        const float* p = B + y0 * RLW;
        LOADROW(p, a);  p += RLW;
        LOADROW(p, b6);
#pragma unroll
        for (int rr = 0; rr < 4; rr++) {
            p += RLW;
            LOADROW(p, c6);
            const int gy = gy0 + y0 + rr;
            float4 dv = make_float4(0.f, 0.f, 0.f, 0.f);
            if ((unsigned)gy < IMG && (unsigned)gxb < IMG)
                dv = *(const float4*)(dimg + gy*IMG + gxb);
            const float dva[4] = {dv.x, dv.y, dv.z, dv.w};
#pragma unroll
            for (int k = 0; k < 4; k++) {
                float s = 0.15f * dva[k];
                s += kk[0]*a[k]  + kk[1]*a[k+1]  + kk[2]*a[k+2];
                s += kk[3]*b6[k] + kk[4]*b6[k+1] + kk[5]*b6[k+2];
                s += kk[6]*c6[k] + kk[7]*c6[k+1] + kk[8]*c6[k+2];
                st[rr*4+k] = s;
            }
#pragma unroll
            for (int q = 0; q < 6; q++) { a[q] = b6[q]; b6[q] = c6[q]; }
        }
    }
    // Valid region [8,120)^2 -> pi,pj in [2,29]; owned cols 4pj..4pj+3.
    if (pi >= 2 && pi <= 29 && pj >= 2 && pj <= 29) {
#pragma unroll
        for (int rr = 0; rr < 4; rr++) {
            const int gy = gy0 + y0 + rr;       // >= 0 (pi>=2)
            if (gy < IMG && gxb + 3 < IMG) {
                float4 v = make_float4(st[rr*4+0], st[rr*4+1],
                                       st[rr*4+2], st[rr*4+3]);
                if (do_clip) {
                    v.x = fminf(fmaxf(v.x, 1e-4f), 1.0f - 1e-4f);
                    v.y = fminf(fmaxf(v.y, 1e-4f), 1.0f - 1e-4f);
                    v.z = fminf(fmaxf(v.z, 1e-4f), 1.0f - 1e-4f);
                    v.w = fminf(fmaxf(v.w, 1e-4f), 1.0f - 1e-4f);
                }
                *(float4*)(oimg + gy*IMG + gxb) = v;
            }
        }
    }
}

// ---------------- Fallback: single-kernel 15-step version (Round-4) ----------
#define TILE  128
#define OFF_Y 16
#define OFF_X 18
#define BUFY  160
#define BUFX  164
#define LW    172
#define NP    1014

__device__ __forceinline__ void read_row6(const float* __restrict__ p, int xw,
                                          float* m) {
    const float4 mid = *(const float4*)(p + xw + 4);
    m[0] = p[xw + 3];
    m[1] = mid.x; m[2] = mid.y; m[3] = mid.z; m[4] = mid.w;
    m[5] = p[xw + 8];
}

__global__ __launch_bounds__(1024, 4) void cml_fused(
    const float* __restrict__ drive,
    const float* __restrict__ Kw,
    float* __restrict__ out)
{
    __shared__ float lds[BUFY * LW];
    const int tid = threadIdx.x;
    const int bid = blockIdx.x;
    const int bc  = bid >> 4;
    const int tl  = bid & 15;
    const int gy0 = (tl >> 2) * TILE - OFF_Y;
    const int gx0 = (tl & 3)  * TILE - OFF_X;
    const float* __restrict__ img  = drive + (size_t)bc * (IMG*IMG);
    float*       __restrict__ oimg = out   + (size_t)bc * (IMG*IMG);
    float kk[9];
    {
        const float c2 = 0.85f * 0.3f;
        const float* kp = Kw + (bc & 3) * 9;
#pragma unroll
        for (int q = 0; q < 9; q++) kk[q] = c2 * kp[q];
        kk[4] += 0.85f * 0.7f;
    }
    const int t2 = tid < NP ? tid : NP - 1;
    const int pi = t2 / 39;
    const int pj = t2 - pi * 39;
    const int y0 = 2 + 6 * pi;
    const int xw = 4 * pj;
    float dvs[24], fx[4], fy[6];
#pragma unroll
    for (int k = 0; k < 4; k++)
        fx[k] = ((unsigned)(gx0 + xw + 4 + k) < IMG) ? 1.0f : 0.0f;
#pragma unroll
    for (int rr = 0; rr < 6; rr++) {
        const int gy = gy0 + y0 + rr;
        fy[rr] = ((unsigned)gy < IMG) ? 1.0f : 0.0f;
#pragma unroll
        for (int k = 0; k < 4; k++) {
            const int gx = gx0 + xw + 4 + k;
            dvs[rr*4+k] = (((unsigned)gy < IMG) && ((unsigned)gx < IMG))
                        ? 0.15f * img[gy*IMG + gx] : 0.0f;
        }
    }
    for (int u = tid; u < BUFY * (LW/2); u += 1024) {
        const int yy = u / (LW/2);
        const int xx = (u - yy * (LW/2)) * 2;
        const int gy = gy0 + yy;
        const int gxb = gx0 + xx;
        float2 v = make_float2(0.f, 0.f);
        if (xx < BUFX && (unsigned)gy < IMG && (unsigned)gxb < IMG)
            v = *(const float2*)(img + gy*IMG + gxb);
        v.x = mapf(v.x); v.y = mapf(v.y);
        *(float2*)(lds + yy*LW + xx) = v;
    }
    __syncthreads();
    float st[24];
#pragma unroll 1
    for (int step = 0; step < 14; step++) {
        {
            float a[6], b[6], c[6];
            const float* p = lds + (y0 - 1) * LW;
            read_row6(p, xw, a);  p += LW;
            read_row6(p, xw, b);
#pragma unroll
            for (int rr = 0; rr < 6; rr++) {
                p += LW;
                read_row6(p, xw, c);
                const float fyr = fy[rr];
#pragma unroll
                for (int k = 0; k < 4; k++) {
                    float s = dvs[rr*4+k];
                    s += kk[0]*a[k] + kk[1]*a[k+1] + kk[2]*a[k+2];
                    s += kk[3]*b[k] + kk[4]*b[k+1] + kk[5]*b[k+2];
                    s += kk[6]*c[k] + kk[7]*c[k+1] + kk[8]*c[k+2];
                    const float t = 3.9f * s;
                    st[rr*4+k] = (t - t*s) * fyr * fx[k];
                }
#pragma unroll
                for (int q = 0; q < 6; q++) { a[q] = b[q]; b[q] = c[q]; }
            }
        }
        __syncthreads();
        {
            float* w = lds + y0 * LW + xw + 4;
#pragma unroll
            for (int rr = 0; rr < 6; rr++) {
                *(float4*)w = make_float4(st[rr*4+0], st[rr*4+1],
                                          st[rr*4+2], st[rr*4+3]);
                w += LW;
            }
        }
        __syncthreads();
    }
    {
        float a[6], b[6], c[6];
        const float* p = lds + (y0 - 1) * LW;
        read_row6(p, xw, a);  p += LW;
        read_row6(p, xw, b);
#pragma unroll
        for (int rr = 0; rr < 6; rr++) {
            p += LW;
            read_row6(p, xw, c);
#pragma unroll
            for (int k = 0; k < 4; k++) {
                float s = dvs[rr*4+k];
                s += kk[0]*a[k] + kk[1]*a[k+1] + kk[2]*a[k+2];
                s += kk[3]*b[k] + kk[4]*b[k+1] + kk[5]*b[k+2];
                s += kk[6]*c[k] + kk[7]*c[k+1] + kk[8]*c[k+2];
                st[rr*4+k] = fminf(fmaxf(s, 1e-4f), 1.0f - 1e-4f);
            }
#pragma unroll
            for (int q = 0; q < 6; q++) { a[q] = b[q]; b[q] = c[q]; }
        }
    }
#pragma unroll
    for (int rr = 0; rr < 6; rr++) {
        const int r = y0 + rr;
        if (r >= OFF_Y && r < OFF_Y + TILE) {
#pragma unroll
            for (int h = 0; h < 2; h++) {
                const int col = xw + 4 + 2*h;
                if (col >= OFF_X && col + 1 < OFF_X + TILE) {
                    *(float2*)(oimg + (size_t)(gy0 + r) * IMG + (gx0 + col)) =
                        make_float2(st[rr*4 + 2*h], st[rr*4 + 2*h + 1]);
                }
            }
        }
    }
}

extern "C" void kernel_launch(void* const* d_in, const int* in_sizes, int n_in,
                              void* d_out, int out_size, void* d_ws, size_t ws_size,
                              hipStream_t stream)
{
    const float* drive = (const float*)d_in[0];
    const float* Kw    = (const float*)d_in[1];
    float* out         = (float*)d_out;
    const size_t need  = (size_t)256 * IMG * IMG * sizeof(float);  // 256 MiB

    if (ws_size >= need) {
        float* g8 = (float*)d_ws;
        // Round 1: g0=drive, 8 steps -> g8 (unclipped) in ws
        cml_round<<<dim3(6400), dim3(1024), 0, stream>>>(drive, drive, Kw, g8, 8, 0);
        // Round 2: g8, 7 steps -> clipped g15 in out
        cml_round<<<dim3(6400), dim3(1024), 0, stream>>>(g8, drive, Kw, out, 7, 1);
    } else {
        cml_fused<<<dim3(4096), dim3(1024), 0, stream>>>(drive, Kw, out);
    }
}

// Round 10
// 831.910 us; speedup vs baseline: 1.8075x; 1.4388x over previous
//
#include <hip/hip_runtime.h>

#define IMG  512
#define TR   48           // output tile rows per block
#define TC   112          // output tile cols per block
#define RH   8            // halo = max steps per round
#define RLW  132          // SoA row stride dwords: s0'[33] s1[32] s2[32] s3'[33] +2 pad
#define PR   66           // phys rows: logical -1..64

__device__ __forceinline__ float mapf(float g) {
    float t = 3.9f * g;
    return t - t * g;     // R*g*(1-g)
}

// SoA col mapping (buffer cols -1..128):
//   col 4j+0 -> s0'[j]   = off j        (j=0..31; j=32 is right-ext col 128)
//   col 4j+1 -> s1[j]    = off 33+j
//   col 4j+2 -> s2[j]    = off 65+j
//   col 4j+3 -> s3'[j+1] = off 98+j     (s3'[0] = off 97 is left-ext col -1)
// Stencil window cols 4pj-1..4pj+4 -> offsets {97+pj, pj, 33+pj, 65+pj, 98+pj, 1+pj}
// -> affine in pj for ALL lanes (no edge selects), stride-1 across lanes.
#define RD(P, M) do {                       \
    const float* _p = (P);                  \
    (M)[0] = _p[97 + pj];                   \
    (M)[1] = _p[pj];                        \
    (M)[2] = _p[33 + pj];                   \
    (M)[3] = _p[65 + pj];                   \
    (M)[4] = _p[98 + pj];                   \
    (M)[5] = _p[1 + pj];                    \
} while (0)

// One temporal round: init M=map(src), run `steps` CML steps, store grid to
// dst (clipped if do_clip). Valid output rows [8,56), cols [8,120) of buffer.
// 512 threads, each owns a 4-wide x 4-tall patch. 34.8 KB LDS -> 4 blocks/CU
// (4 barrier domains, 100% wave occupancy); ~60 live VGPRs fits the 64
// budget the allocator targets at 8 waves/SIMD.
__global__ __launch_bounds__(512) void cml_round(
    const float* __restrict__ src,
    const float* __restrict__ drv,
    const float* __restrict__ Kw,
    float* __restrict__ dst,
    int steps, int do_clip)
{
    __shared__ float B[PR * RLW];      // 34.8 KiB

    const int tid = threadIdx.x;
    const int bid = blockIdx.x;
    const int bc  = bid / 55;               // image*channel index
    const int tl  = bid % 55;               // 11 row-strips x 5 col-tiles
    const int gy0 = (tl / 5) * TR - RH;     // logical buffer row 0 -> gy0
    const int gx0 = (tl % 5) * TC - RH;     // multiple of 4
    const float* __restrict__ simg = src + (size_t)bc * (IMG*IMG);
    const float* __restrict__ dimg = drv + (size_t)bc * (IMG*IMG);
    float*       __restrict__ oimg = dst + (size_t)bc * (IMG*IMG);

    // Folded 3x3 kernel: K' = (0.85*0.3)*K + (0.85*0.7)*delta_center.
    // bc is block-uniform -> scalarizes to SGPRs.
    float kk[9];
    {
        const float c2 = 0.85f * 0.3f;
        const float* kp = Kw + (bc & 3) * 9;
#pragma unroll
        for (int q = 0; q < 9; q++) kk[q] = c2 * kp[q];
        kk[4] += 0.85f * 0.7f;
    }

    const int pj  = tid & 31;               // col patch: owned cols 4pj..4pj+3
    const int pi  = tid >> 5;               // row band:  owned rows 4pi..4pi+3
    const int y0  = pi * 4;
    const int gxb = gx0 + pj * 4;           // global col of owned float4
    // 4-aligned tile + 4-aligned image: owned float4 is all-in or all-out.
    const float fxc = ((unsigned)gxb < IMG) ? 1.0f : 0.0f;

    // beta*drive for owned cells, hoisted to registers (zero per-step cost)
    float dvs[16];
#pragma unroll
    for (int rr = 0; rr < 4; rr++) {
        const int gy = gy0 + y0 + rr;
        float4 dv = make_float4(0.f, 0.f, 0.f, 0.f);
        if ((unsigned)gy < IMG && (unsigned)gxb < IMG)
            dv = *(const float4*)(dimg + gy*IMG + gxb);
        dvs[rr*4+0] = 0.15f * dv.x;
        dvs[rr*4+1] = 0.15f * dv.y;
        dvs[rr*4+2] = 0.15f * dv.z;
        dvs[rr*4+3] = 0.15f * dv.w;
    }

    // Init: B = map(src) over phys rows 0..65 (logical -1..64), SoA layout.
    for (int u = tid; u < PR * 32; u += 512) {
        const int r = u >> 5;
        const int p = u & 31;
        const int gy  = gy0 + r - 1;
        const int gxq = gx0 + p * 4;
        const bool rowok = (unsigned)gy < IMG;
        float4 v = make_float4(0.f, 0.f, 0.f, 0.f);
        if (rowok && (unsigned)gxq < IMG)
            v = *(const float4*)(simg + gy*IMG + gxq);   // gxq<=508: no row cross
        float* row = B + r * RLW;
        row[p]      = mapf(v.x);
        row[33 + p] = mapf(v.y);
        row[65 + p] = mapf(v.z);
        row[98 + p] = mapf(v.w);
        if (p == 0) {                        // left-ext col -1 -> s3'[0]
            float e = (rowok && (unsigned)(gx0 - 1) < IMG)
                    ? simg[gy*IMG + gx0 - 1] : 0.f;
            row[97] = mapf(e);
        }
        if (p == 31) {                       // right-ext col 128 -> s0'[32]
            float e = (rowok && (unsigned)(gx0 + 128) < IMG)
                    ? simg[gy*IMG + gx0 + 128] : 0.f;
            row[32] = mapf(e);
        }
    }
    __syncthreads();

    float st[16];
#pragma unroll 1
    for (int step = 0; step < steps - 1; step++) {
        {
            float a[6], b6[6], c6[6];
            const float* p = B + y0 * RLW;      // phys y0 = logical y0-1
            RD(p, a);  p += RLW;
            RD(p, b6);
#pragma unroll
            for (int rr = 0; rr < 4; rr++) {
                p += RLW;
                RD(p, c6);
                const float ff = (((unsigned)(gy0 + y0 + rr) < IMG) ? 1.0f : 0.0f) * fxc;
#pragma unroll
                for (int k = 0; k < 4; k++) {
                    float s = dvs[rr*4+k];
                    s += kk[0]*a[k]  + kk[1]*a[k+1]  + kk[2]*a[k+2];
                    s += kk[3]*b6[k] + kk[4]*b6[k+1] + kk[5]*b6[k+2];
                    s += kk[6]*c6[k] + kk[7]*c6[k+1] + kk[8]*c6[k+2];
                    const float t = 3.9f * s;
                    st[rr*4+k] = (t - t*s) * ff;
                }
#pragma unroll
                for (int q = 0; q < 6; q++) { a[q] = b6[q]; b6[q] = c6[q]; }
            }
        }
        __syncthreads();   // all reads done before any write (WAR)
#pragma unroll
        for (int rr = 0; rr < 4; rr++) {
            float* w = B + (y0 + 1 + rr) * RLW;    // phys = logical+1
            w[pj]      = st[rr*4+0];
            w[33 + pj] = st[rr*4+1];
            w[65 + pj] = st[rr*4+2];
            w[98 + pj] = st[rr*4+3];
        }
        __syncthreads();   // writes done before next step's reads (RAW)
    }

    // Final step of the round: compute grid (no map), store valid interior.
    {
        float a[6], b6[6], c6[6];
        const float* p = B + y0 * RLW;
        RD(p, a);  p += RLW;
        RD(p, b6);
#pragma unroll
        for (int rr = 0; rr < 4; rr++) {
            p += RLW;
            RD(p, c6);
#pragma unroll
            for (int k = 0; k < 4; k++) {
                float s = dvs[rr*4+k];
                s += kk[0]*a[k]  + kk[1]*a[k+1]  + kk[2]*a[k+2];
                s += kk[3]*b6[k] + kk[4]*b6[k+1] + kk[5]*b6[k+2];
                s += kk[6]*c6[k] + kk[7]*c6[k+1] + kk[8]*c6[k+2];
                st[rr*4+k] = s;
            }
#pragma unroll
            for (int q = 0; q < 6; q++) { a[q] = b6[q]; b6[q] = c6[q]; }
        }
    }
    // Valid region: rows [8,56) -> pi in [2,13]; cols [8,120) -> pj in [2,29].
    if (pi >= 2 && pi <= 13 && pj >= 2 && pj <= 29) {
#pragma unroll
        for (int rr = 0; rr < 4; rr++) {
            const int gy = gy0 + y0 + rr;       // >= 0 (pi>=2, gy0>=-8)
            if (gy < IMG && gxb + 3 < IMG) {    // gxb >= 0 (pj>=2)
                float4 v = make_float4(st[rr*4+0], st[rr*4+1],
                                       st[rr*4+2], st[rr*4+3]);
                if (do_clip) {
                    v.x = fminf(fmaxf(v.x, 1e-4f), 1.0f - 1e-4f);
                    v.y = fminf(fmaxf(v.y, 1e-4f), 1.0f - 1e-4f);
                    v.z = fminf(fmaxf(v.z, 1e-4f), 1.0f - 1e-4f);
                    v.w = fminf(fmaxf(v.w, 1e-4f), 1.0f - 1e-4f);
                }
                *(float4*)(oimg + gy*IMG + gxb) = v;
            }
        }
    }
}

// ---------------- Fallback: single-kernel 15-step version (Round-4) ----------
#define TILE  128
#define OFF_Y 16
#define OFF_X 18
#define BUFY  160
#define BUFX  164
#define LW    172
#define NP    1014

__device__ __forceinline__ void read_row6(const float* __restrict__ p, int xw,
                                          float* m) {
    const float4 mid = *(const float4*)(p + xw + 4);
    m[0] = p[xw + 3];
    m[1] = mid.x; m[2] = mid.y; m[3] = mid.z; m[4] = mid.w;
    m[5] = p[xw + 8];
}

__global__ __launch_bounds__(1024, 4) void cml_fused(
    const float* __restrict__ drive,
    const float* __restrict__ Kw,
    float* __restrict__ out)
{
    __shared__ float lds[BUFY * LW];
    const int tid = threadIdx.x;
    const int bid = blockIdx.x;
    const int bc  = bid >> 4;
    const int tl  = bid & 15;
    const int gy0 = (tl >> 2) * TILE - OFF_Y;
    const int gx0 = (tl & 3)  * TILE - OFF_X;
    const float* __restrict__ img  = drive + (size_t)bc * (IMG*IMG);
    float*       __restrict__ oimg = out   + (size_t)bc * (IMG*IMG);
    float kk[9];
    {
        const float c2 = 0.85f * 0.3f;
        const float* kp = Kw + (bc & 3) * 9;
#pragma unroll
        for (int q = 0; q < 9; q++) kk[q] = c2 * kp[q];
        kk[4] += 0.85f * 0.7f;
    }
    const int t2 = tid < NP ? tid : NP - 1;
    const int pi = t2 / 39;
    const int pj = t2 - pi * 39;
    const int y0 = 2 + 6 * pi;
    const int xw = 4 * pj;
    float dvs[24], fx[4], fy[6];
#pragma unroll
    for (int k = 0; k < 4; k++)
        fx[k] = ((unsigned)(gx0 + xw + 4 + k) < IMG) ? 1.0f : 0.0f;
#pragma unroll
    for (int rr = 0; rr < 6; rr++) {
        const int gy = gy0 + y0 + rr;
        fy[rr] = ((unsigned)gy < IMG) ? 1.0f : 0.0f;
#pragma unroll
        for (int k = 0; k < 4; k++) {
            const int gx = gx0 + xw + 4 + k;
            dvs[rr*4+k] = (((unsigned)gy < IMG) && ((unsigned)gx < IMG))
                        ? 0.15f * img[gy*IMG + gx] : 0.0f;
        }
    }
    for (int u = tid; u < BUFY * (LW/2); u += 1024) {
        const int yy = u / (LW/2);
        const int xx = (u - yy * (LW/2)) * 2;
        const int gy = gy0 + yy;
        const int gxb = gx0 + xx;
        float2 v = make_float2(0.f, 0.f);
        if (xx < BUFX && (unsigned)gy < IMG && (unsigned)gxb < IMG)
            v = *(const float2*)(img + gy*IMG + gxb);
        v.x = mapf(v.x); v.y = mapf(v.y);
        *(float2*)(lds + yy*LW + xx) = v;
    }
    __syncthreads();
    float st[24];
#pragma unroll 1
    for (int step = 0; step < 14; step++) {
        {
            float a[6], b[6], c[6];
            const float* p = lds + (y0 - 1) * LW;
            read_row6(p, xw, a);  p += LW;
            read_row6(p, xw, b);
#pragma unroll
            for (int rr = 0; rr < 6; rr++) {
                p += LW;
                read_row6(p, xw, c);
                const float fyr = fy[rr];
#pragma unroll
                for (int k = 0; k < 4; k++) {
                    float s = dvs[rr*4+k];
                    s += kk[0]*a[k] + kk[1]*a[k+1] + kk[2]*a[k+2];
                    s += kk[3]*b[k] + kk[4]*b[k+1] + kk[5]*b[k+2];
                    s += kk[6]*c[k] + kk[7]*c[k+1] + kk[8]*c[k+2];
                    const float t = 3.9f * s;
                    st[rr*4+k] = (t - t*s) * fyr * fx[k];
                }
#pragma unroll
                for (int q = 0; q < 6; q++) { a[q] = b[q]; b[q] = c[q]; }
            }
        }
        __syncthreads();
        {
            float* w = lds + y0 * LW + xw + 4;
#pragma unroll
            for (int rr = 0; rr < 6; rr++) {
                *(float4*)w = make_float4(st[rr*4+0], st[rr*4+1],
                                          st[rr*4+2], st[rr*4+3]);
                w += LW;
            }
        }
        __syncthreads();
    }
    {
        float a[6], b[6], c[6];
        const float* p = lds + (y0 - 1) * LW;
        read_row6(p, xw, a);  p += LW;
        read_row6(p, xw, b);
#pragma unroll
        for (int rr = 0; rr < 6; rr++) {
            p += LW;
            read_row6(p, xw, c);
#pragma unroll
            for (int k = 0; k < 4; k++) {
                float s = dvs[rr*4+k];
                s += kk[0]*a[k] + kk[1]*a[k+1] + kk[2]*a[k+2];
                s += kk[3]*b[k] + kk[4]*b[k+1] + kk[5]*b[k+2];
                s += kk[6]*c[k] + kk[7]*c[k+1] + kk[8]*c[k+2];
                st[rr*4+k] = fminf(fmaxf(s, 1e-4f), 1.0f - 1e-4f);
            }
#pragma unroll
            for (int q = 0; q < 6; q++) { a[q] = b[q]; b[q] = c[q]; }
        }
    }
#pragma unroll
    for (int rr = 0; rr < 6; rr++) {
        const int r = y0 + rr;
        if (r >= OFF_Y && r < OFF_Y + TILE) {
#pragma unroll
            for (int h = 0; h < 2; h++) {
                const int col = xw + 4 + 2*h;
                if (col >= OFF_X && col + 1 < OFF_X + TILE) {
                    *(float2*)(oimg + (size_t)(gy0 + r) * IMG + (gx0 + col)) =
                        make_float2(st[rr*4 + 2*h], st[rr*4 + 2*h + 1]);
                }
            }
        }
    }
}

extern "C" void kernel_launch(void* const* d_in, const int* in_sizes, int n_in,
                              void* d_out, int out_size, void* d_ws, size_t ws_size,
                              hipStream_t stream)
{
    const float* drive = (const float*)d_in[0];
    const float* Kw    = (const float*)d_in[1];
    float* out         = (float*)d_out;
    const size_t need  = (size_t)256 * IMG * IMG * sizeof(float);  // 256 MiB

    if (ws_size >= need) {
        float* g8 = (float*)d_ws;
        // 256 images x 55 tiles (11 row-strips x 5 col-tiles) = 14080 blocks
        // Round 1: g0=drive, 8 steps -> g8 (unclipped) in ws
        cml_round<<<dim3(14080), dim3(512), 0, stream>>>(drive, drive, Kw, g8, 8, 0);
        // Round 2: g8, 7 steps -> clipped g15 in out
        cml_round<<<dim3(14080), dim3(512), 0, stream>>>(g8, drive, Kw, out, 7, 1);
    } else {
        cml_fused<<<dim3(4096), dim3(1024), 0, stream>>>(drive, Kw, out);
    }
}